// Round 8
// baseline (473.130 us; speedup 1.0000x reference)
//
#include <hip/hip_runtime.h>
#include <math.h>

// FlowLayer: 2 steps of manifold (S^2) graph heat flow.
// N=50000 nodes, C=16 channels, D=3, E=1.6M edges.
//
// Build: 8-way privatized histogram, 16 atomics in flight per thread (hist),
// 3-phase scan, atomic-free fill (8 edges/thread) with packed (rcv,w) 8B
// scatter. Replica id = (edge_group & 7), identical in hist and fill.
//
// Flow (channel-major path): x transposed to [C][N,3]. Block = 64 nodes x 4
// edge-slots; the block's CSR slice is staged into LDS ONCE and reused for
// all 16 channels. Gathers for channel c hit a 600KB slice -> L2-resident.
// Fallback (small ws): R7 wave-per-node flow on [N,C,3].
//
// NOTE: |u|^2 MUST be computed from u's components (not 1-cs^2): near
// antipodal pairs 1-cs^2 cancels catastrophically -> rsq explodes (R5 bug).

constexpr float EPS64F = 2.2204460492503131e-16f;  // np.float64 eps
constexpr float PI_F   = 3.14159265358979323846f;
constexpr int   NREP   = 8;
constexpr int   EDGE_CAP = 4096;  // LDS-staged pairs per 64-node block (32KB)

typedef int   vi4 __attribute__((ext_vector_type(4)));
typedef float vf4 __attribute__((ext_vector_type(4)));

// ---------------- CSR build ----------------

// 16 edges per thread (4 interleaved vi4 groups) -> 16 atomics in flight.
__global__ __launch_bounds__(256) void hist_kernel(
    const vi4* __restrict__ snd4, int* __restrict__ rep,
    vi4* __restrict__ pos4, const int* __restrict__ snd,
    int* __restrict__ pos, int N, int E) {
  int tid = threadIdx.x;
  int E4 = E >> 2;
  #pragma unroll
  for (int gg = 0; gg < 4; ++gg) {
    int g = blockIdx.x * 1024 + gg * 256 + tid;  // coalesced per inner load
    if (g < E4) {
      int rb = (g & (NREP - 1)) * N;  // replica id: must match fill_kernel
      vi4 s = __builtin_nontemporal_load(&snd4[g]);
      vi4 p;
      p.x = atomicAdd(&rep[rb + s.x], 1);
      p.y = atomicAdd(&rep[rb + s.y], 1);
      p.z = atomicAdd(&rep[rb + s.z], 1);
      p.w = atomicAdd(&rep[rb + s.w], 1);
      __builtin_nontemporal_store(p, &pos4[g]);
    }
  }
  if (blockIdx.x == 0 && tid == 0) {  // scalar tail (E % 4) -> replica 0
    for (int e = E4 << 2; e < E; ++e) pos[e] = atomicAdd(&rep[snd[e]], 1);
  }
}

// Phase A: fold 8 replicas per node (exclusive prefix over replicas written
// back in place), then per-1024-tile exclusive scan of node totals.
__global__ __launch_bounds__(1024) void scanA_kernel(
    int* __restrict__ rep, int* __restrict__ row_start,
    int* __restrict__ btot, int N) {
  __shared__ int wsum[16];
  int tid = threadIdx.x;
  int lane = tid & 63, wave = tid >> 6;
  int i = blockIdx.x * 1024 + tid;
  int v = 0;
  if (i < N) {
    int run = 0;
    int cpre[NREP];
    #pragma unroll
    for (int r = 0; r < NREP; ++r) {
      int t = rep[r * N + i];
      cpre[r] = run;
      run += t;
    }
    v = run;
    #pragma unroll
    for (int r = 0; r < NREP; ++r) rep[r * N + i] = cpre[r];
  }
  int incl = v;
  #pragma unroll
  for (int off = 1; off < 64; off <<= 1) {
    int t = __shfl_up(incl, off, 64);
    if (lane >= off) incl += t;
  }
  if (lane == 63) wsum[wave] = incl;
  __syncthreads();
  if (wave == 0 && lane < 16) {
    int wincl = wsum[lane];
    #pragma unroll
    for (int off = 1; off < 16; off <<= 1) {
      int t = __shfl_up(wincl, off, 64);
      if (lane >= off) wincl += t;
    }
    wsum[lane] = wincl;
  }
  __syncthreads();
  int woff = (wave > 0) ? wsum[wave - 1] : 0;
  if (i < N) row_start[i] = woff + incl - v;  // tile-local exclusive
  if (tid == 0) btot[blockIdx.x] = wsum[15];
}

__global__ __launch_bounds__(64) void scanB_kernel(
    const int* __restrict__ btot, int* __restrict__ boff,
    int* __restrict__ row_start, int nb, int N) {
  int lane = threadIdx.x;
  int v = (lane < nb) ? btot[lane] : 0;
  int incl = v;
  #pragma unroll
  for (int off = 1; off < 64; off <<= 1) {
    int t = __shfl_up(incl, off, 64);
    if (lane >= off) incl += t;
  }
  if (lane < nb) boff[lane] = incl - v;
  if (lane == 63) row_start[N] = incl;  // grand total (scanC skips index N)
}

__global__ __launch_bounds__(1024) void scanC_kernel(
    int* __restrict__ row_start, const int* __restrict__ boff,
    int* __restrict__ rep, int N) {
  int i = blockIdx.x * 1024 + threadIdx.x;
  if (i < N) {
    int rs = row_start[i] + boff[blockIdx.x];
    row_start[i] = rs;
    #pragma unroll
    for (int r = 0; r < NREP; ++r) rep[r * N + i] += rs;
  }
}

// Atomic-free fill: 8 edges per thread (2 interleaved vi4 groups).
__global__ __launch_bounds__(256) void fill_kernel(
    const vi4* __restrict__ snd4, const vi4* __restrict__ rcv4,
    const vf4* __restrict__ ew4, const vi4* __restrict__ pos4,
    const int* __restrict__ rep, long long* __restrict__ pair,
    const int* __restrict__ snd, const int* __restrict__ rcv,
    const float* __restrict__ ew, const int* __restrict__ pos, int N, int E) {
  int tid = threadIdx.x;
  int E4 = E >> 2;
  #pragma unroll
  for (int gg = 0; gg < 2; ++gg) {
    int g = blockIdx.x * 512 + gg * 256 + tid;
    if (g < E4) {
      int rb = (g & (NREP - 1)) * N;  // must match hist_kernel
      vi4 s = __builtin_nontemporal_load(&snd4[g]);
      vi4 r = __builtin_nontemporal_load(&rcv4[g]);
      vf4 w = __builtin_nontemporal_load(&ew4[g]);
      vi4 p = __builtin_nontemporal_load(&pos4[g]);
      pair[rep[rb + s.x] + p.x] =
          (long long)(((unsigned long long)(unsigned)__float_as_int(w.x) << 32) | (unsigned)r.x);
      pair[rep[rb + s.y] + p.y] =
          (long long)(((unsigned long long)(unsigned)__float_as_int(w.y) << 32) | (unsigned)r.y);
      pair[rep[rb + s.z] + p.z] =
          (long long)(((unsigned long long)(unsigned)__float_as_int(w.z) << 32) | (unsigned)r.z);
      pair[rep[rb + s.w] + p.w] =
          (long long)(((unsigned long long)(unsigned)__float_as_int(w.w) << 32) | (unsigned)r.w);
    }
  }
  if (blockIdx.x == 0 && tid == 0) {  // scalar tail -> replica 0
    for (int e = E4 << 2; e < E; ++e) {
      pair[rep[snd[e]] + pos[e]] =
          (long long)(((unsigned long long)(unsigned)__float_as_int(ew[e]) << 32) | (unsigned)rcv[e]);
    }
  }
}

// ---------------- transposes ----------------

// nodes [N][48] -> xT [16][N][3]; tile padded to stride 49 (bank spread).
__global__ __launch_bounds__(256) void tfwd_kernel(
    const float* __restrict__ x, float* __restrict__ xT, int N) {
  __shared__ float tile[64 * 49];
  int tid = threadIdx.x;
  int b0 = blockIdx.x * 64;
  int nmax = min(64, N - b0);
  int total = nmax * 48;
  const float* src = x + (size_t)b0 * 48;
  for (int i = tid; i < total; i += 256) {
    int nl = i / 48, jj = i - nl * 48;
    tile[nl * 49 + jj] = src[i];
  }
  __syncthreads();
  for (int i = tid; i < 3072; i += 256) {
    int c = i / 192;               // 192 = 64*3
    int rem = i - c * 192;
    int nl = rem / 3;
    int d = rem - nl * 3;
    if (nl < nmax)
      xT[(size_t)c * N * 3 + (size_t)(b0 + nl) * 3 + d] = tile[nl * 49 + c * 3 + d];
  }
}

// zT [16][N][3] -> out [N][48]
__global__ __launch_bounds__(256) void tbwd_kernel(
    const float* __restrict__ xT, float* __restrict__ x, int N) {
  __shared__ float tile[64 * 49];
  int tid = threadIdx.x;
  int b0 = blockIdx.x * 64;
  int nmax = min(64, N - b0);
  for (int i = tid; i < 3072; i += 256) {
    int c = i / 192;
    int rem = i - c * 192;
    int nl = rem / 3;
    int d = rem - nl * 3;
    if (nl < nmax)
      tile[nl * 49 + c * 3 + d] = xT[(size_t)c * N * 3 + (size_t)(b0 + nl) * 3 + d];
  }
  __syncthreads();
  float* dst = x + (size_t)b0 * 48;
  int total = nmax * 48;
  for (int i = tid; i < total; i += 256) {
    int nl = i / 48, jj = i - nl * 48;
    dst[i] = tile[nl * 49 + jj];
  }
}

// ---------------- flow ----------------

__device__ __forceinline__ void edge_accum(
    float p0, float p1, float p2, float q0, float q1, float q2, float w,
    float& a0, float& a1, float& a2) {
  float cs = fminf(1.0f, fmaxf(-1.0f, fmaf(p0, q0, fmaf(p1, q1, p2 * q2))));
  float u0 = fmaf(-cs, p0, q0);
  float u1 = fmaf(-cs, p1, q1);
  float u2 = fmaf(-cs, p2, q2);
  // |u|^2 from components: no cancellation near cs=+-1, coef*u <= w*theta.
  float un2 = fmaxf(fmaf(u0, u0, fmaf(u1, u1, u2 * u2)), 1e-24f);
  // acos via A&S 4.4.45 (|err| <= 6.7e-5; output threshold is 2e-2)
  float ax = fabsf(cs);
  float s = sqrtf(1.0f - ax);
  float poly = fmaf(ax, fmaf(ax, fmaf(ax, -0.0187293f, 0.0742610f),
                             -0.2121144f), 1.5707288f);
  float th = s * poly;
  float theta = (cs >= 0.0f) ? th : (PI_F - th);
  float coef = w * theta * __builtin_amdgcn_rsqf(un2);
  a0 = fmaf(coef, u0, a0);
  a1 = fmaf(coef, u1, a1);
  a2 = fmaf(coef, u2, a2);
}

__device__ __forceinline__ void node_update(
    float a0, float a1, float a2, float ws, float p0, float p1, float p2,
    float ts, float dsv, float* dst) {
  // v_lap = -agg/deg; nrm/scale sign-invariant; -(v_lap*scale)*t = +g*scale*t
  float invdg = __builtin_amdgcn_rcpf(ws + 1e-12f);
  float g0 = a0 * invdg, g1 = a1 * invdg, g2 = a2 * invdg;
  float nrm = sqrtf(fmaf(g0, g0, fmaf(g1, g1, g2 * g2)) + EPS64F);
  float tch = ts * ts * 0.5f;  // t_sqrt^2 / N_STEPS
  float dch = dsv * dsv;
  float alp = __builtin_amdgcn_rcpf(1.0f + __expf(dch - nrm));  // sigmoid
  float scale = (nrm * alp <= 1.0f) ? alp : __builtin_amdgcn_rcpf(nrm);
  float f = scale * tch;
  float v0 = g0 * f, v1 = g1 * f, v2 = g2 * f;
  float nv = sqrtf(fmaf(v0, v0, fmaf(v1, v1, v2 * v2)));
  float cn = __cosf(nv);
  float sc = (nv > 1e-20f) ? (__sinf(nv) * __builtin_amdgcn_rcpf(nv)) : 1.0f;
  float y0 = fmaf(cn, p0, sc * v0);
  float y1 = fmaf(cn, p1, sc * v1);
  float y2 = fmaf(cn, p2, sc * v2);
  float inv = __builtin_amdgcn_rsqf(fmaf(y0, y0, fmaf(y1, y1, y2 * y2)));
  dst[0] = y0 * inv;
  dst[1] = y1 * inv;
  dst[2] = y2 * inv;
}

// Channel-major flow: block = 64 nodes x 4 edge-slots; CSR slice staged to
// LDS once, reused across all 16 channels; gathers hit 600KB channel slice.
__global__ __launch_bounds__(256) void flowcm_kernel(
    const float* __restrict__ xT, const int* __restrict__ row_start,
    const long long* __restrict__ pair, const float* __restrict__ tsq,
    const float* __restrict__ dsq, float* __restrict__ yT, int N) {
  __shared__ long long spair[EDGE_CAP];
  int tid = threadIdx.x;
  int nloc = tid >> 2, k = tid & 3;
  int b0 = blockIdx.x * 64;
  int n = b0 + nloc;
  int blkbeg = row_start[b0];
  int blkend = row_start[min(b0 + 64, N)];
  int staged = min(blkend - blkbeg, EDGE_CAP);
  for (int i = tid; i < staged; i += 256) spair[i] = pair[blkbeg + i];
  int beg = 0, end = 0;
  if (n < N) { beg = row_start[n]; end = row_start[n + 1]; }
  __syncthreads();
  #pragma unroll 1
  for (int c = 0; c < 16; ++c) {
    const float* xc = xT + (size_t)c * N * 3;
    float p0 = 0.f, p1 = 0.f, p2 = 0.f;
    if (n < N) { p0 = xc[n * 3]; p1 = xc[n * 3 + 1]; p2 = xc[n * 3 + 2]; }
    float a0 = 0.f, a1 = 0.f, a2 = 0.f, ws = 0.f;
    for (int j = beg + k; j < end; j += 4) {
      int idx = j - blkbeg;
      long long e = (idx < staged) ? spair[idx]
                                   : __builtin_nontemporal_load(&pair[j]);
      int r = (int)e;
      float w = __int_as_float((int)(e >> 32));
      const float* q = xc + r * 3;
      edge_accum(p0, p1, p2, q[0], q[1], q[2], w, a0, a1, a2);
      ws += w;
    }
    // reduce the 4 edge-slots (quad lanes: xor 1, 2 — same wave)
    a0 += __shfl_xor(a0, 1); a1 += __shfl_xor(a1, 1);
    a2 += __shfl_xor(a2, 1); ws += __shfl_xor(ws, 1);
    a0 += __shfl_xor(a0, 2); a1 += __shfl_xor(a1, 2);
    a2 += __shfl_xor(a2, 2); ws += __shfl_xor(ws, 2);
    if (k == 0 && n < N) {
      node_update(a0, a1, a2, ws, p0, p1, p2, tsq[c], dsq[c],
                  yT + (size_t)c * N * 3 + (size_t)n * 3);
    }
  }
}

// Fallback flow (R7): [N,C,3] layout, 1 wave per node, lane=(k*16+c).
__global__ __launch_bounds__(256) void flownc_kernel(
    const float* __restrict__ xin, const int* __restrict__ row_start,
    const long long* __restrict__ pair, const float* __restrict__ tsq,
    const float* __restrict__ dsq, float* __restrict__ xout, int N) {
  int node = blockIdx.x * 4 + (threadIdx.x >> 6);
  if (node >= N) return;
  int lane = threadIdx.x & 63;
  int c = lane & 15;
  int k = lane >> 4;
  int beg = row_start[node];
  int end = row_start[node + 1];
  int ip = node * 48 + c * 3;
  float p0 = xin[ip + 0], p1 = xin[ip + 1], p2 = xin[ip + 2];
  float a0 = 0.f, a1 = 0.f, a2 = 0.f, ws = 0.f;
  int iters = (end - beg + 7) >> 3;
  int lastj = end - 1;
  int j = beg + k;
  for (int t = 0; t < iters; ++t, j += 8) {
    int jA = j, jB = j + 4;
    long long eA = __builtin_nontemporal_load(&pair[min(jA, lastj)]);
    long long eB = __builtin_nontemporal_load(&pair[min(jB, lastj)]);
    int rA = (int)eA;
    int rB = (int)eB;
    float wA = (jA < end) ? __int_as_float((int)(eA >> 32)) : 0.f;
    float wB = (jB < end) ? __int_as_float((int)(eB >> 32)) : 0.f;
    const float* qA = xin + rA * 48 + c * 3;
    const float* qB = xin + rB * 48 + c * 3;
    float qA0 = qA[0], qA1 = qA[1], qA2 = qA[2];
    float qB0 = qB[0], qB1 = qB[1], qB2 = qB[2];
    edge_accum(p0, p1, p2, qA0, qA1, qA2, wA, a0, a1, a2);
    edge_accum(p0, p1, p2, qB0, qB1, qB2, wB, a0, a1, a2);
    ws += wA + wB;
  }
  a0 += __shfl_xor(a0, 16); a1 += __shfl_xor(a1, 16);
  a2 += __shfl_xor(a2, 16); ws += __shfl_xor(ws, 16);
  a0 += __shfl_xor(a0, 32); a1 += __shfl_xor(a1, 32);
  a2 += __shfl_xor(a2, 32); ws += __shfl_xor(ws, 32);
  if (k == 0) node_update(a0, a1, a2, ws, p0, p1, p2, tsq[c], dsq[c], xout + ip);
}

extern "C" void kernel_launch(void* const* d_in, const int* in_sizes, int n_in,
                              void* d_out, int out_size, void* d_ws, size_t ws_size,
                              hipStream_t stream) {
  const float* nodes = (const float*)d_in[0];  // [N,16,3]
  const float* ew    = (const float*)d_in[1];  // [E]
  const float* tsq   = (const float*)d_in[2];  // [16]
  const float* dsq   = (const float*)d_in[3];  // [16]
  const int*   snd   = (const int*)d_in[4];    // [E]
  const int*   rcv   = (const int*)d_in[5];    // [E]
  float* out = (float*)d_out;

  int E = in_sizes[1];
  int N = in_sizes[0] / 48;

  // workspace (bytes): rep | row_start | btot | boff | pair | xT | yT(pos)
  size_t repB  = (size_t)NREP * N * 4;
  size_t rsB   = (size_t)(N + 4) * 4;
  size_t auxB  = 128 * 4;
  size_t pairB = (size_t)E * 8;
  size_t xTB   = (size_t)N * 48 * 4;
  size_t zzB   = xTB > (size_t)E * 4 ? xTB : (size_t)E * 4;  // yT | pos union
  size_t need_cm = repB + rsB + auxB + pairB + xTB + zzB;

  char* base = (char*)d_ws;
  int*       rep       = (int*)base;
  int*       row_start = (int*)(base + repB);
  int*       btot      = (int*)(base + repB + rsB);
  int*       boff      = btot + 64;
  long long* pair      = (long long*)(base + repB + rsB + auxB);
  float*     xT        = (float*)(base + repB + rsB + auxB + pairB);
  float*     yT        = (float*)(base + repB + rsB + auxB + pairB + xTB);
  bool cm = (ws_size >= need_cm);
  // fallback layout: pos/xtmp union directly after pair (fits: R7 proven)
  int*   pos  = cm ? (int*)yT : (int*)xT;
  float* xtmp = (float*)pos;

  hipMemsetAsync(rep, 0, repB, stream);

  int E4 = E >> 2;
  int hb = (E4 + 1023) / 1024;
  int fb = (E4 + 511) / 512;
  int nb = (N + 1023) / 1024;
  int tb = (N + 63) / 64;
  int nfb = (N + 3) / 4;

  if (cm) tfwd_kernel<<<tb, 256, 0, stream>>>(nodes, xT, N);
  hist_kernel<<<hb, 256, 0, stream>>>((const vi4*)snd, rep, (vi4*)pos,
                                      snd, pos, N, E);
  scanA_kernel<<<nb, 1024, 0, stream>>>(rep, row_start, btot, N);
  scanB_kernel<<<1, 64, 0, stream>>>(btot, boff, row_start, nb, N);
  scanC_kernel<<<nb, 1024, 0, stream>>>(row_start, boff, rep, N);
  fill_kernel<<<fb, 256, 0, stream>>>((const vi4*)snd, (const vi4*)rcv,
                                      (const vf4*)ew, (const vi4*)pos,
                                      rep, pair, snd, rcv, ew, pos, N, E);

  if (cm) {
    // step1: xT -> yT ; step2: yT -> zT (reuse xT region) ; transpose back
    flowcm_kernel<<<tb, 256, 0, stream>>>(xT, row_start, pair, tsq, dsq, yT, N);
    flowcm_kernel<<<tb, 256, 0, stream>>>(yT, row_start, pair, tsq, dsq, xT, N);
    tbwd_kernel<<<tb, 256, 0, stream>>>(xT, out, N);
  } else {
    flownc_kernel<<<nfb, 256, 0, stream>>>(nodes, row_start, pair, tsq, dsq, xtmp, N);
    flownc_kernel<<<nfb, 256, 0, stream>>>(xtmp, row_start, pair, tsq, dsq, out, N);
  }
}

// Round 9
// 329.349 us; speedup vs baseline: 1.4366x; 1.4366x over previous
//
#include <hip/hip_runtime.h>
#include <math.h>

// FlowLayer: 2 steps of manifold (S^2) graph heat flow.
// N=50000 nodes, C=16 channels, D=3, E=1.6M edges.
//
// Build: 8-way privatized histogram (1 atomic/edge, ~25G/s ceiling), 3-phase
// scan, atomic-free fill with packed (rcv,w) 8B scatter + 16 zero sentinels.
//
// Flow: wave per node, lane=(k*16+c), 16 edges/wave-iter (4 slots x 4-unroll).
// Gathers read a compact fp16 copy xh [N][16][4] halves (128B rows, 6.4MB);
// p and the rare near-antipodal recompute use fp32 (R5 lesson: |u|^2 from
// components; fp16 q direction noise guarded by un2<1e-4 -> fp32 refetch).
// Step1 writes fp32+fp16 copies; step2 writes fp32 out.

constexpr float EPS64F = 2.2204460492503131e-16f;  // np.float64 eps
constexpr float PI_F   = 3.14159265358979323846f;
constexpr int   NREP   = 8;

typedef int      vi4 __attribute__((ext_vector_type(4)));
typedef float    vf4 __attribute__((ext_vector_type(4)));
typedef _Float16 vh4 __attribute__((ext_vector_type(4)));

// ---------------- CSR build ----------------

__global__ __launch_bounds__(256) void hist_kernel(
    const vi4* __restrict__ snd4, int* __restrict__ rep,
    vi4* __restrict__ pos4, const int* __restrict__ snd,
    int* __restrict__ pos, int N, int E) {
  int tid = threadIdx.x;
  int E4 = E >> 2;
  #pragma unroll
  for (int gg = 0; gg < 4; ++gg) {
    int g = blockIdx.x * 1024 + gg * 256 + tid;
    if (g < E4) {
      int rb = (g & (NREP - 1)) * N;  // replica id: must match fill_kernel
      vi4 s = __builtin_nontemporal_load(&snd4[g]);
      vi4 p;
      p.x = atomicAdd(&rep[rb + s.x], 1);
      p.y = atomicAdd(&rep[rb + s.y], 1);
      p.z = atomicAdd(&rep[rb + s.z], 1);
      p.w = atomicAdd(&rep[rb + s.w], 1);
      __builtin_nontemporal_store(p, &pos4[g]);
    }
  }
  if (blockIdx.x == 0 && tid == 0) {  // scalar tail (E % 4) -> replica 0
    for (int e = E4 << 2; e < E; ++e) pos[e] = atomicAdd(&rep[snd[e]], 1);
  }
}

// Phase A: fold 8 replicas/node (exclusive prefix written back), tile scan.
__global__ __launch_bounds__(1024) void scanA_kernel(
    int* __restrict__ rep, int* __restrict__ row_start,
    int* __restrict__ btot, int N) {
  __shared__ int wsum[16];
  int tid = threadIdx.x;
  int lane = tid & 63, wave = tid >> 6;
  int i = blockIdx.x * 1024 + tid;
  int v = 0;
  if (i < N) {
    int run = 0;
    int cpre[NREP];
    #pragma unroll
    for (int r = 0; r < NREP; ++r) {
      int t = rep[r * N + i];
      cpre[r] = run;
      run += t;
    }
    v = run;
    #pragma unroll
    for (int r = 0; r < NREP; ++r) rep[r * N + i] = cpre[r];
  }
  int incl = v;
  #pragma unroll
  for (int off = 1; off < 64; off <<= 1) {
    int t = __shfl_up(incl, off, 64);
    if (lane >= off) incl += t;
  }
  if (lane == 63) wsum[wave] = incl;
  __syncthreads();
  if (wave == 0 && lane < 16) {
    int wincl = wsum[lane];
    #pragma unroll
    for (int off = 1; off < 16; off <<= 1) {
      int t = __shfl_up(wincl, off, 64);
      if (lane >= off) wincl += t;
    }
    wsum[lane] = wincl;
  }
  __syncthreads();
  int woff = (wave > 0) ? wsum[wave - 1] : 0;
  if (i < N) row_start[i] = woff + incl - v;
  if (tid == 0) btot[blockIdx.x] = wsum[15];
}

__global__ __launch_bounds__(64) void scanB_kernel(
    const int* __restrict__ btot, int* __restrict__ boff,
    int* __restrict__ row_start, int nb, int N) {
  int lane = threadIdx.x;
  int v = (lane < nb) ? btot[lane] : 0;
  int incl = v;
  #pragma unroll
  for (int off = 1; off < 64; off <<= 1) {
    int t = __shfl_up(incl, off, 64);
    if (lane >= off) incl += t;
  }
  if (lane < nb) boff[lane] = incl - v;
  if (lane == 63) row_start[N] = incl;  // grand total
}

__global__ __launch_bounds__(1024) void scanC_kernel(
    int* __restrict__ row_start, const int* __restrict__ boff,
    int* __restrict__ rep, int N) {
  int i = blockIdx.x * 1024 + threadIdx.x;
  if (i < N) {
    int rs = row_start[i] + boff[blockIdx.x];
    row_start[i] = rs;
    #pragma unroll
    for (int r = 0; r < NREP; ++r) rep[r * N + i] += rs;
  }
}

// Atomic-free fill: 8 edges/thread; writes 16 zero sentinels past pair[E].
__global__ __launch_bounds__(256) void fill_kernel(
    const vi4* __restrict__ snd4, const vi4* __restrict__ rcv4,
    const vf4* __restrict__ ew4, const vi4* __restrict__ pos4,
    const int* __restrict__ rep, long long* __restrict__ pair,
    const int* __restrict__ snd, const int* __restrict__ rcv,
    const float* __restrict__ ew, const int* __restrict__ pos, int N, int E) {
  int tid = threadIdx.x;
  int E4 = E >> 2;
  #pragma unroll
  for (int gg = 0; gg < 2; ++gg) {
    int g = blockIdx.x * 512 + gg * 256 + tid;
    if (g < E4) {
      int rb = (g & (NREP - 1)) * N;  // must match hist_kernel
      vi4 s = __builtin_nontemporal_load(&snd4[g]);
      vi4 r = __builtin_nontemporal_load(&rcv4[g]);
      vf4 w = __builtin_nontemporal_load(&ew4[g]);
      vi4 p = __builtin_nontemporal_load(&pos4[g]);
      pair[rep[rb + s.x] + p.x] =
          (long long)(((unsigned long long)(unsigned)__float_as_int(w.x) << 32) | (unsigned)r.x);
      pair[rep[rb + s.y] + p.y] =
          (long long)(((unsigned long long)(unsigned)__float_as_int(w.y) << 32) | (unsigned)r.y);
      pair[rep[rb + s.z] + p.z] =
          (long long)(((unsigned long long)(unsigned)__float_as_int(w.z) << 32) | (unsigned)r.z);
      pair[rep[rb + s.w] + p.w] =
          (long long)(((unsigned long long)(unsigned)__float_as_int(w.w) << 32) | (unsigned)r.w);
    }
  }
  if (blockIdx.x == 0 && tid == 0) {
    for (int e = E4 << 2; e < E; ++e) {  // scalar tail -> replica 0
      pair[rep[snd[e]] + pos[e]] =
          (long long)(((unsigned long long)(unsigned)__float_as_int(ew[e]) << 32) | (unsigned)rcv[e]);
    }
    for (int z = 0; z < 16; ++z) pair[(size_t)E + z] = 0;  // sentinels (w=0)
  }
}

// ---------------- fp32 -> fp16 staging copy ----------------

// xf [N][48] -> xh [N][16][4] halves (pad 4th). thread = n*16+c.
__global__ __launch_bounds__(256) void tconv_kernel(
    const float* __restrict__ xf, _Float16* __restrict__ xh, int NC) {
  int t = blockIdx.x * 256 + threadIdx.x;
  if (t >= NC) return;
  float a = xf[t * 3], b = xf[t * 3 + 1], d = xf[t * 3 + 2];
  vh4 h;
  h.x = (_Float16)a; h.y = (_Float16)b; h.z = (_Float16)d; h.w = (_Float16)0.f;
  *(vh4*)(xh + (size_t)t * 4) = h;
}

// ---------------- flow ----------------

__device__ __forceinline__ void edge_accum_f(
    float p0, float p1, float p2, float q0, float q1, float q2, float w,
    float& a0, float& a1, float& a2) {
  float cs = fminf(1.0f, fmaxf(-1.0f, fmaf(p0, q0, fmaf(p1, q1, p2 * q2))));
  float u0 = fmaf(-cs, p0, q0);
  float u1 = fmaf(-cs, p1, q1);
  float u2 = fmaf(-cs, p2, q2);
  float un2 = fmaxf(fmaf(u0, u0, fmaf(u1, u1, u2 * u2)), 1e-24f);
  float ax = fabsf(cs);
  float s = sqrtf(1.0f - ax);
  float poly = fmaf(ax, fmaf(ax, fmaf(ax, -0.0187293f, 0.0742610f),
                             -0.2121144f), 1.5707288f);
  float th = s * poly;
  float theta = (cs >= 0.0f) ? th : (PI_F - th);
  float coef = w * theta * __builtin_amdgcn_rsqf(un2);
  a0 = fmaf(coef, u0, a0);
  a1 = fmaf(coef, u1, a1);
  a2 = fmaf(coef, u2, a2);
}

// fp16 gather + fp32 guard for |u|^2 < 1e-4 (direction noise regime).
__device__ __forceinline__ void edge_accum_h(
    float p0, float p1, float p2, const _Float16* __restrict__ xh,
    const float* __restrict__ xf, int r, int c, float w,
    float& a0, float& a1, float& a2) {
  vh4 qh = *(const vh4*)(xh + ((size_t)r * 16 + c) * 4);
  float q0 = (float)qh.x, q1 = (float)qh.y, q2 = (float)qh.z;
  float cs = fminf(1.0f, fmaxf(-1.0f, fmaf(p0, q0, fmaf(p1, q1, p2 * q2))));
  float u0 = fmaf(-cs, p0, q0);
  float u1 = fmaf(-cs, p1, q1);
  float u2 = fmaf(-cs, p2, q2);
  float un2 = fmaf(u0, u0, fmaf(u1, u1, u2 * u2));
  if (un2 < 1e-4f && w > 0.f) {  // rare (~2.5K/51M): redo edge in fp32
    const float* q = xf + (size_t)r * 48 + c * 3;
    q0 = q[0]; q1 = q[1]; q2 = q[2];
    cs = fminf(1.0f, fmaxf(-1.0f, fmaf(p0, q0, fmaf(p1, q1, p2 * q2))));
    u0 = fmaf(-cs, p0, q0);
    u1 = fmaf(-cs, p1, q1);
    u2 = fmaf(-cs, p2, q2);
    un2 = fmaf(u0, u0, fmaf(u1, u1, u2 * u2));
  }
  un2 = fmaxf(un2, 1e-24f);
  float ax = fabsf(cs);
  float s = sqrtf(1.0f - ax);
  float poly = fmaf(ax, fmaf(ax, fmaf(ax, -0.0187293f, 0.0742610f),
                             -0.2121144f), 1.5707288f);
  float th = s * poly;
  float theta = (cs >= 0.0f) ? th : (PI_F - th);
  float coef = w * theta * __builtin_amdgcn_rsqf(un2);
  a0 = fmaf(coef, u0, a0);
  a1 = fmaf(coef, u1, a1);
  a2 = fmaf(coef, u2, a2);
}

__device__ __forceinline__ void node_step(
    float a0, float a1, float a2, float ws, float p0, float p1, float p2,
    float ts, float dsv, float& y0, float& y1, float& y2) {
  // v_lap = -agg/deg; nrm/scale sign-invariant; -(v_lap*scale)*t = +g*scale*t
  float invdg = __builtin_amdgcn_rcpf(ws + 1e-12f);
  float g0 = a0 * invdg, g1 = a1 * invdg, g2 = a2 * invdg;
  float nrm = sqrtf(fmaf(g0, g0, fmaf(g1, g1, g2 * g2)) + EPS64F);
  float tch = ts * ts * 0.5f;  // t_sqrt^2 / N_STEPS
  float dch = dsv * dsv;
  float alp = __builtin_amdgcn_rcpf(1.0f + __expf(dch - nrm));  // sigmoid
  float scale = (nrm * alp <= 1.0f) ? alp : __builtin_amdgcn_rcpf(nrm);
  float f = scale * tch;
  float v0 = g0 * f, v1 = g1 * f, v2 = g2 * f;
  float nv = sqrtf(fmaf(v0, v0, fmaf(v1, v1, v2 * v2)));
  float cn = __cosf(nv);
  float sc = (nv > 1e-20f) ? (__sinf(nv) * __builtin_amdgcn_rcpf(nv)) : 1.0f;
  float t0 = fmaf(cn, p0, sc * v0);
  float t1 = fmaf(cn, p1, sc * v1);
  float t2 = fmaf(cn, p2, sc * v2);
  float inv = __builtin_amdgcn_rsqf(fmaf(t0, t0, fmaf(t1, t1, t2 * t2)));
  y0 = t0 * inv; y1 = t1 * inv; y2 = t2 * inv;
}

// Wave per node; lane = k*16 + c; 16 edges/wave-iter (4 slots x 4-unroll).
// Gathers via fp16 xh; p + guard via fp32 xf. writeh: also emit fp16 copy.
__global__ __launch_bounds__(256) void flowh_kernel(
    const _Float16* __restrict__ xh, const float* __restrict__ xf,
    const int* __restrict__ row_start, const long long* __restrict__ pair,
    const float* __restrict__ tsq, const float* __restrict__ dsq,
    float* __restrict__ yf, _Float16* __restrict__ yh, int N, int writeh) {
  int node = blockIdx.x * 4 + (threadIdx.x >> 6);
  if (node >= N) return;
  int lane = threadIdx.x & 63;
  int c = lane & 15;
  int k = lane >> 4;
  int beg = row_start[node];
  int end = row_start[node + 1];
  int ip = node * 48 + c * 3;
  float p0 = xf[ip], p1 = xf[ip + 1], p2 = xf[ip + 2];
  float a0 = 0.f, a1 = 0.f, a2 = 0.f, ws = 0.f;
  int iters = (end - beg + 15) >> 4;
  int j = beg + k;
  for (int t = 0; t < iters; ++t, j += 16) {
    // pair padded with 16 zero sentinels; interior overrun masked by w=0.
    long long e0 = __builtin_nontemporal_load(&pair[j]);
    long long e1 = __builtin_nontemporal_load(&pair[j + 4]);
    long long e2 = __builtin_nontemporal_load(&pair[j + 8]);
    long long e3 = __builtin_nontemporal_load(&pair[j + 12]);
    float w0 = (j      < end) ? __int_as_float((int)(e0 >> 32)) : 0.f;
    float w1 = (j + 4  < end) ? __int_as_float((int)(e1 >> 32)) : 0.f;
    float w2 = (j + 8  < end) ? __int_as_float((int)(e2 >> 32)) : 0.f;
    float w3 = (j + 12 < end) ? __int_as_float((int)(e3 >> 32)) : 0.f;
    int r0 = (int)e0, r1 = (int)e1, r2 = (int)e2, r3 = (int)e3;
    edge_accum_h(p0, p1, p2, xh, xf, r0, c, w0, a0, a1, a2);
    edge_accum_h(p0, p1, p2, xh, xf, r1, c, w1, a0, a1, a2);
    edge_accum_h(p0, p1, p2, xh, xf, r2, c, w2, a0, a1, a2);
    edge_accum_h(p0, p1, p2, xh, xf, r3, c, w3, a0, a1, a2);
    ws += (w0 + w1) + (w2 + w3);
  }
  a0 += __shfl_xor(a0, 16); a1 += __shfl_xor(a1, 16);
  a2 += __shfl_xor(a2, 16); ws += __shfl_xor(ws, 16);
  a0 += __shfl_xor(a0, 32); a1 += __shfl_xor(a1, 32);
  a2 += __shfl_xor(a2, 32); ws += __shfl_xor(ws, 32);
  if (k == 0) {
    float y0, y1, y2;
    node_step(a0, a1, a2, ws, p0, p1, p2, tsq[c], dsq[c], y0, y1, y2);
    yf[ip] = y0; yf[ip + 1] = y1; yf[ip + 2] = y2;
    if (writeh) {
      vh4 h;
      h.x = (_Float16)y0; h.y = (_Float16)y1; h.z = (_Float16)y2;
      h.w = (_Float16)0.f;
      *(vh4*)(yh + ((size_t)node * 16 + c) * 4) = h;
    }
  }
}

// Fallback (small ws): pure-fp32 R7 flow.
__global__ __launch_bounds__(256) void flownc_kernel(
    const float* __restrict__ xin, const int* __restrict__ row_start,
    const long long* __restrict__ pair, const float* __restrict__ tsq,
    const float* __restrict__ dsq, float* __restrict__ xout, int N) {
  int node = blockIdx.x * 4 + (threadIdx.x >> 6);
  if (node >= N) return;
  int lane = threadIdx.x & 63;
  int c = lane & 15;
  int k = lane >> 4;
  int beg = row_start[node];
  int end = row_start[node + 1];
  int ip = node * 48 + c * 3;
  float p0 = xin[ip], p1 = xin[ip + 1], p2 = xin[ip + 2];
  float a0 = 0.f, a1 = 0.f, a2 = 0.f, ws = 0.f;
  int iters = (end - beg + 7) >> 3;
  int j = beg + k;
  for (int t = 0; t < iters; ++t, j += 8) {
    long long eA = __builtin_nontemporal_load(&pair[j]);
    long long eB = __builtin_nontemporal_load(&pair[j + 4]);
    int rA = (int)eA, rB = (int)eB;
    float wA = (j     < end) ? __int_as_float((int)(eA >> 32)) : 0.f;
    float wB = (j + 4 < end) ? __int_as_float((int)(eB >> 32)) : 0.f;
    const float* qA = xin + rA * 48 + c * 3;
    const float* qB = xin + rB * 48 + c * 3;
    edge_accum_f(p0, p1, p2, qA[0], qA[1], qA[2], wA, a0, a1, a2);
    edge_accum_f(p0, p1, p2, qB[0], qB[1], qB[2], wB, a0, a1, a2);
    ws += wA + wB;
  }
  a0 += __shfl_xor(a0, 16); a1 += __shfl_xor(a1, 16);
  a2 += __shfl_xor(a2, 16); ws += __shfl_xor(ws, 16);
  a0 += __shfl_xor(a0, 32); a1 += __shfl_xor(a1, 32);
  a2 += __shfl_xor(a2, 32); ws += __shfl_xor(ws, 32);
  if (k == 0) {
    float y0, y1, y2;
    node_step(a0, a1, a2, ws, p0, p1, p2, tsq[c], dsq[c], y0, y1, y2);
    xout[ip] = y0; xout[ip + 1] = y1; xout[ip + 2] = y2;
  }
}

static inline size_t al16(size_t x) { return (x + 15) & ~(size_t)15; }

extern "C" void kernel_launch(void* const* d_in, const int* in_sizes, int n_in,
                              void* d_out, int out_size, void* d_ws, size_t ws_size,
                              hipStream_t stream) {
  const float* nodes = (const float*)d_in[0];  // [N,16,3]
  const float* ew    = (const float*)d_in[1];  // [E]
  const float* tsq   = (const float*)d_in[2];  // [16]
  const float* dsq   = (const float*)d_in[3];  // [16]
  const int*   snd   = (const int*)d_in[4];    // [E]
  const int*   rcv   = (const int*)d_in[5];    // [E]
  float* out = (float*)d_out;

  int E = in_sizes[1];
  int N = in_sizes[0] / 48;

  size_t repB  = al16((size_t)NREP * N * 4);
  size_t rsB   = al16((size_t)(N + 4) * 4);
  size_t auxB  = 512;
  size_t pairB = al16((size_t)(E + 16) * 8);
  size_t xhB   = al16((size_t)N * 64 * 2);   // [N][16][4] halves
  size_t xf1B  = al16((size_t)N * 48 * 4);
  size_t posB  = al16((size_t)E * 4);
  size_t zB    = (posB > xhB) ? posB : xhB;  // pos | xh1 union (disjoint lifetime)
  size_t need_h  = repB + rsB + auxB + pairB + xhB + xf1B + zB;
  size_t z32B    = (posB > xf1B) ? posB : xf1B;
  size_t need_32 = repB + rsB + auxB + pairB + z32B;

  char* base = (char*)d_ws;
  int*       rep       = (int*)base;
  int*       row_start = (int*)(base + repB);
  int*       btot      = (int*)(base + repB + rsB);
  int*       boff      = btot + 64;
  long long* pair      = (long long*)(base + repB + rsB + auxB);
  char*      after     = base + repB + rsB + auxB + pairB;

  bool hpath = (ws_size >= need_h);
  _Float16* xh0  = (_Float16*)after;                  // h-path
  float*    xf1  = (float*)(after + xhB);             // h-path
  char*     zreg = after + xhB + xf1B;                // h-path: pos | xh1
  int*      pos  = hpath ? (int*)zreg : (int*)after;  // fallback: pos | xtmp
  _Float16* xh1  = (_Float16*)zreg;
  float*    xtmp = (float*)after;

  hipMemsetAsync(rep, 0, repB, stream);

  int E4 = E >> 2;
  int hb  = (E4 + 1023) / 1024;
  int fbk = (E4 + 511) / 512;
  int nb  = (N + 1023) / 1024;
  int cb  = (N * 16 + 255) / 256;
  int nfb = (N + 3) / 4;

  if (hpath) tconv_kernel<<<cb, 256, 0, stream>>>(nodes, xh0, N * 16);
  hist_kernel<<<hb, 256, 0, stream>>>((const vi4*)snd, rep, (vi4*)pos,
                                      snd, pos, N, E);
  scanA_kernel<<<nb, 1024, 0, stream>>>(rep, row_start, btot, N);
  scanB_kernel<<<1, 64, 0, stream>>>(btot, boff, row_start, nb, N);
  scanC_kernel<<<nb, 1024, 0, stream>>>(row_start, boff, rep, N);
  fill_kernel<<<fbk, 256, 0, stream>>>((const vi4*)snd, (const vi4*)rcv,
                                       (const vf4*)ew, (const vi4*)pos,
                                       rep, pair, snd, rcv, ew, pos, N, E);

  if (hpath) {
    // step1: (xh0, nodes) -> (xf1, xh1) ; step2: (xh1, xf1) -> out
    flowh_kernel<<<nfb, 256, 0, stream>>>(xh0, nodes, row_start, pair,
                                          tsq, dsq, xf1, xh1, N, 1);
    flowh_kernel<<<nfb, 256, 0, stream>>>(xh1, xf1, row_start, pair,
                                          tsq, dsq, out, (_Float16*)0, N, 0);
  } else {
    (void)need_32;
    flownc_kernel<<<nfb, 256, 0, stream>>>(nodes, row_start, pair, tsq, dsq, xtmp, N);
    flownc_kernel<<<nfb, 256, 0, stream>>>(xtmp, row_start, pair, tsq, dsq, out, N);
  }
}

// Round 10
// 309.053 us; speedup vs baseline: 1.5309x; 1.0657x over previous
//
#include <hip/hip_runtime.h>
#include <math.h>

// FlowLayer: 2 steps of manifold (S^2) graph heat flow.
// N=50000 nodes, C=16 channels, D=3, E=1.6M edges.
//
// Build: 8-way privatized histogram (1 atomic/edge, ~25G/s memory-side RMW
// ceiling - measured R6/R7), 3-phase scan, atomic-free fill with packed
// (w, rcv*48) 8B scatter + 16 zero sentinels. rcv premultiplied by 48 so the
// flow loop has no per-edge multiply.
//
// Flow: fp32 (R9 lesson: fp16 gather cut bytes but added cvt VALU work and
// regressed; this kernel is VALU-issue-bound, not BW-bound). Wave per node,
// lane=(k*16+c), 16 edges/wave-iter = 4 slots x 2 packed float2 pairs.
// Edge math done on float2 ext-vectors to engage v_pk_fma_f32 dual-issue.
//
// NOTE: |u|^2 MUST be computed from u's components (not 1-cs^2): near
// antipodal pairs 1-cs^2 cancels catastrophically -> rsq explodes (R5 bug).

constexpr float EPS64F = 2.2204460492503131e-16f;  // np.float64 eps
constexpr float PI_F   = 3.14159265358979323846f;
constexpr int   NREP   = 8;

typedef int   vi4 __attribute__((ext_vector_type(4)));
typedef float vf4 __attribute__((ext_vector_type(4)));
typedef float vf2 __attribute__((ext_vector_type(2)));

// ---------------- CSR build ----------------

__global__ __launch_bounds__(256) void hist_kernel(
    const vi4* __restrict__ snd4, int* __restrict__ rep,
    vi4* __restrict__ pos4, const int* __restrict__ snd,
    int* __restrict__ pos, int N, int E) {
  int tid = threadIdx.x;
  int E4 = E >> 2;
  #pragma unroll
  for (int gg = 0; gg < 4; ++gg) {
    int g = blockIdx.x * 1024 + gg * 256 + tid;
    if (g < E4) {
      int rb = (g & (NREP - 1)) * N;  // replica id: must match fill_kernel
      vi4 s = __builtin_nontemporal_load(&snd4[g]);
      vi4 p;
      p.x = atomicAdd(&rep[rb + s.x], 1);
      p.y = atomicAdd(&rep[rb + s.y], 1);
      p.z = atomicAdd(&rep[rb + s.z], 1);
      p.w = atomicAdd(&rep[rb + s.w], 1);
      __builtin_nontemporal_store(p, &pos4[g]);
    }
  }
  if (blockIdx.x == 0 && tid == 0) {  // scalar tail (E % 4) -> replica 0
    for (int e = E4 << 2; e < E; ++e) pos[e] = atomicAdd(&rep[snd[e]], 1);
  }
}

// Phase A: fold 8 replicas/node (exclusive prefix written back), tile scan.
__global__ __launch_bounds__(1024) void scanA_kernel(
    int* __restrict__ rep, int* __restrict__ row_start,
    int* __restrict__ btot, int N) {
  __shared__ int wsum[16];
  int tid = threadIdx.x;
  int lane = tid & 63, wave = tid >> 6;
  int i = blockIdx.x * 1024 + tid;
  int v = 0;
  if (i < N) {
    int run = 0;
    int cpre[NREP];
    #pragma unroll
    for (int r = 0; r < NREP; ++r) {
      int t = rep[r * N + i];
      cpre[r] = run;
      run += t;
    }
    v = run;
    #pragma unroll
    for (int r = 0; r < NREP; ++r) rep[r * N + i] = cpre[r];
  }
  int incl = v;
  #pragma unroll
  for (int off = 1; off < 64; off <<= 1) {
    int t = __shfl_up(incl, off, 64);
    if (lane >= off) incl += t;
  }
  if (lane == 63) wsum[wave] = incl;
  __syncthreads();
  if (wave == 0 && lane < 16) {
    int wincl = wsum[lane];
    #pragma unroll
    for (int off = 1; off < 16; off <<= 1) {
      int t = __shfl_up(wincl, off, 64);
      if (lane >= off) wincl += t;
    }
    wsum[lane] = wincl;
  }
  __syncthreads();
  int woff = (wave > 0) ? wsum[wave - 1] : 0;
  if (i < N) row_start[i] = woff + incl - v;
  if (tid == 0) btot[blockIdx.x] = wsum[15];
}

__global__ __launch_bounds__(64) void scanB_kernel(
    const int* __restrict__ btot, int* __restrict__ boff,
    int* __restrict__ row_start, int nb, int N) {
  int lane = threadIdx.x;
  int v = (lane < nb) ? btot[lane] : 0;
  int incl = v;
  #pragma unroll
  for (int off = 1; off < 64; off <<= 1) {
    int t = __shfl_up(incl, off, 64);
    if (lane >= off) incl += t;
  }
  if (lane < nb) boff[lane] = incl - v;
  if (lane == 63) row_start[N] = incl;  // grand total
}

__global__ __launch_bounds__(1024) void scanC_kernel(
    int* __restrict__ row_start, const int* __restrict__ boff,
    int* __restrict__ rep, int N) {
  int i = blockIdx.x * 1024 + threadIdx.x;
  if (i < N) {
    int rs = row_start[i] + boff[blockIdx.x];
    row_start[i] = rs;
    #pragma unroll
    for (int r = 0; r < NREP; ++r) rep[r * N + i] += rs;
  }
}

// Atomic-free fill: packs (w, rcv*48); writes 16 zero sentinels past pair[E].
__global__ __launch_bounds__(256) void fill_kernel(
    const vi4* __restrict__ snd4, const vi4* __restrict__ rcv4,
    const vf4* __restrict__ ew4, const vi4* __restrict__ pos4,
    const int* __restrict__ rep, long long* __restrict__ pair,
    const int* __restrict__ snd, const int* __restrict__ rcv,
    const float* __restrict__ ew, const int* __restrict__ pos, int N, int E) {
  int tid = threadIdx.x;
  int E4 = E >> 2;
  #pragma unroll
  for (int gg = 0; gg < 2; ++gg) {
    int g = blockIdx.x * 512 + gg * 256 + tid;
    if (g < E4) {
      int rb = (g & (NREP - 1)) * N;  // must match hist_kernel
      vi4 s = __builtin_nontemporal_load(&snd4[g]);
      vi4 r = __builtin_nontemporal_load(&rcv4[g]);
      vf4 w = __builtin_nontemporal_load(&ew4[g]);
      vi4 p = __builtin_nontemporal_load(&pos4[g]);
      pair[rep[rb + s.x] + p.x] =
          (long long)(((unsigned long long)(unsigned)__float_as_int(w.x) << 32) | (unsigned)(r.x * 48));
      pair[rep[rb + s.y] + p.y] =
          (long long)(((unsigned long long)(unsigned)__float_as_int(w.y) << 32) | (unsigned)(r.y * 48));
      pair[rep[rb + s.z] + p.z] =
          (long long)(((unsigned long long)(unsigned)__float_as_int(w.z) << 32) | (unsigned)(r.z * 48));
      pair[rep[rb + s.w] + p.w] =
          (long long)(((unsigned long long)(unsigned)__float_as_int(w.w) << 32) | (unsigned)(r.w * 48));
    }
  }
  if (blockIdx.x == 0 && tid == 0) {
    for (int e = E4 << 2; e < E; ++e) {  // scalar tail -> replica 0
      pair[rep[snd[e]] + pos[e]] =
          (long long)(((unsigned long long)(unsigned)__float_as_int(ew[e]) << 32) | (unsigned)(rcv[e] * 48));
    }
    for (int z = 0; z < 16; ++z) pair[(size_t)E + z] = 0;  // sentinels (w=0)
  }
}

// ---------------- flow ----------------

// Packed 2-edge log-map accumulate: float2 lanes -> v_pk_fma_f32 dual issue.
__device__ __forceinline__ void edge_accum_pk(
    vf2 p0, vf2 p1, vf2 p2, vf2 q0, vf2 q1, vf2 q2, vf2 w,
    vf2& a0, vf2& a1, vf2& a2) {
  vf2 cs = p0 * q0 + p1 * q1 + p2 * q2;
  cs = __builtin_elementwise_min(vf2{1.f, 1.f},
       __builtin_elementwise_max(vf2{-1.f, -1.f}, cs));
  vf2 u0 = q0 - cs * p0;
  vf2 u1 = q1 - cs * p1;
  vf2 u2 = q2 - cs * p2;
  // |u|^2 from components (R5 lesson)
  vf2 un2 = __builtin_elementwise_max(u0 * u0 + u1 * u1 + u2 * u2,
                                      vf2{1e-24f, 1e-24f});
  // acos via A&S 4.4.45 (|err| <= 6.7e-5; output threshold is 2e-2)
  vf2 ax = __builtin_elementwise_abs(cs);
  vf2 s = __builtin_elementwise_sqrt(vf2{1.f, 1.f} - ax);
  vf2 poly = ((ax * -0.0187293f + 0.0742610f) * ax - 0.2121144f) * ax
             + 1.5707288f;
  vf2 th = s * poly;
  vf2 theta;
  theta.x = (cs.x >= 0.0f) ? th.x : (PI_F - th.x);
  theta.y = (cs.y >= 0.0f) ? th.y : (PI_F - th.y);
  vf2 rsq;
  rsq.x = __builtin_amdgcn_rsqf(un2.x);
  rsq.y = __builtin_amdgcn_rsqf(un2.y);
  vf2 coef = w * theta * rsq;
  a0 += coef * u0;
  a1 += coef * u1;
  a2 += coef * u2;
}

__device__ __forceinline__ void node_step(
    float a0, float a1, float a2, float ws, float p0, float p1, float p2,
    float ts, float dsv, float& y0, float& y1, float& y2) {
  // v_lap = -agg/deg; nrm/scale sign-invariant; -(v_lap*scale)*t = +g*scale*t
  float invdg = __builtin_amdgcn_rcpf(ws + 1e-12f);
  float g0 = a0 * invdg, g1 = a1 * invdg, g2 = a2 * invdg;
  float nrm = sqrtf(fmaf(g0, g0, fmaf(g1, g1, g2 * g2)) + EPS64F);
  float tch = ts * ts * 0.5f;  // t_sqrt^2 / N_STEPS
  float dch = dsv * dsv;
  float alp = __builtin_amdgcn_rcpf(1.0f + __expf(dch - nrm));  // sigmoid
  float scale = (nrm * alp <= 1.0f) ? alp : __builtin_amdgcn_rcpf(nrm);
  float f = scale * tch;
  float v0 = g0 * f, v1 = g1 * f, v2 = g2 * f;
  float nv = sqrtf(fmaf(v0, v0, fmaf(v1, v1, v2 * v2)));
  float cn = __cosf(nv);
  float sc = (nv > 1e-20f) ? (__sinf(nv) * __builtin_amdgcn_rcpf(nv)) : 1.0f;
  float t0 = fmaf(cn, p0, sc * v0);
  float t1 = fmaf(cn, p1, sc * v1);
  float t2 = fmaf(cn, p2, sc * v2);
  float inv = __builtin_amdgcn_rsqf(fmaf(t0, t0, fmaf(t1, t1, t2 * t2)));
  y0 = t0 * inv; y1 = t1 * inv; y2 = t2 * inv;
}

// Wave per node; lane = k*16 + c; 16 edges/wave-iter (4 slots x 2 pk-pairs).
// pair entries hold (w, rcv*48); sentinels make overruns w=0 reads of node 0.
__global__ __launch_bounds__(256) void flowp_kernel(
    const float* __restrict__ xin, const int* __restrict__ row_start,
    const long long* __restrict__ pair, const float* __restrict__ tsq,
    const float* __restrict__ dsq, float* __restrict__ xout, int N) {
  int node = blockIdx.x * 4 + (threadIdx.x >> 6);
  if (node >= N) return;
  int lane = threadIdx.x & 63;
  int c = lane & 15;
  int k = lane >> 4;
  int c3 = c * 3;
  int beg = row_start[node];
  int end = row_start[node + 1];
  int ip = node * 48 + c3;
  float ps0 = xin[ip], ps1 = xin[ip + 1], ps2 = xin[ip + 2];
  vf2 p0 = {ps0, ps0}, p1 = {ps1, ps1}, p2 = {ps2, ps2};
  vf2 a0 = {0.f, 0.f}, a1 = {0.f, 0.f}, a2 = {0.f, 0.f}, wsv = {0.f, 0.f};
  int iters = (end - beg + 15) >> 4;
  int j = beg + k;
  for (int t = 0; t < iters; ++t, j += 16) {
    long long e0 = __builtin_nontemporal_load(&pair[j]);
    long long e1 = __builtin_nontemporal_load(&pair[j + 4]);
    long long e2 = __builtin_nontemporal_load(&pair[j + 8]);
    long long e3 = __builtin_nontemporal_load(&pair[j + 12]);
    float w0 = (j      < end) ? __int_as_float((int)(e0 >> 32)) : 0.f;
    float w1 = (j + 4  < end) ? __int_as_float((int)(e1 >> 32)) : 0.f;
    float w2 = (j + 8  < end) ? __int_as_float((int)(e2 >> 32)) : 0.f;
    float w3 = (j + 12 < end) ? __int_as_float((int)(e3 >> 32)) : 0.f;
    const float* q0p = xin + ((int)e0 + c3);
    const float* q1p = xin + ((int)e1 + c3);
    const float* q2p = xin + ((int)e2 + c3);
    const float* q3p = xin + ((int)e3 + c3);
    float qa0 = q0p[0], qa1 = q0p[1], qa2 = q0p[2];
    float qb0 = q1p[0], qb1 = q1p[1], qb2 = q1p[2];
    float qc0 = q2p[0], qc1 = q2p[1], qc2 = q2p[2];
    float qd0 = q3p[0], qd1 = q3p[1], qd2 = q3p[2];
    vf2 wA = {w0, w1}, wB = {w2, w3};
    edge_accum_pk(p0, p1, p2, vf2{qa0, qb0}, vf2{qa1, qb1}, vf2{qa2, qb2},
                  wA, a0, a1, a2);
    edge_accum_pk(p0, p1, p2, vf2{qc0, qd0}, vf2{qc1, qd1}, vf2{qc2, qd2},
                  wB, a0, a1, a2);
    wsv += wA + wB;
  }
  float A0 = a0.x + a0.y, A1 = a1.x + a1.y, A2 = a2.x + a2.y;
  float ws = wsv.x + wsv.y;
  A0 += __shfl_xor(A0, 16); A1 += __shfl_xor(A1, 16);
  A2 += __shfl_xor(A2, 16); ws += __shfl_xor(ws, 16);
  A0 += __shfl_xor(A0, 32); A1 += __shfl_xor(A1, 32);
  A2 += __shfl_xor(A2, 32); ws += __shfl_xor(ws, 32);
  if (k == 0) {
    float y0, y1, y2;
    node_step(A0, A1, A2, ws, ps0, ps1, ps2, tsq[c], dsq[c], y0, y1, y2);
    xout[ip] = y0; xout[ip + 1] = y1; xout[ip + 2] = y2;
  }
}

static inline size_t al16(size_t x) { return (x + 15) & ~(size_t)15; }

extern "C" void kernel_launch(void* const* d_in, const int* in_sizes, int n_in,
                              void* d_out, int out_size, void* d_ws, size_t ws_size,
                              hipStream_t stream) {
  const float* nodes = (const float*)d_in[0];  // [N,16,3]
  const float* ew    = (const float*)d_in[1];  // [E]
  const float* tsq   = (const float*)d_in[2];  // [16]
  const float* dsq   = (const float*)d_in[3];  // [16]
  const int*   snd   = (const int*)d_in[4];    // [E]
  const int*   rcv   = (const int*)d_in[5];    // [E]
  float* out = (float*)d_out;

  int E = in_sizes[1];
  int N = in_sizes[0] / 48;

  // workspace: rep[8N] | row_start[N+4] | aux | pair[E+16] | Z
  // Z union: pos[E] (hist->fill) and xtmp[N*48] (flow1->flow2)
  size_t repB  = al16((size_t)NREP * N * 4);
  size_t rsB   = al16((size_t)(N + 4) * 4);
  size_t auxB  = 512;
  size_t pairB = al16((size_t)(E + 16) * 8);

  char* base = (char*)d_ws;
  int*       rep       = (int*)base;
  int*       row_start = (int*)(base + repB);
  int*       btot      = (int*)(base + repB + rsB);
  int*       boff      = btot + 64;
  long long* pair      = (long long*)(base + repB + rsB + auxB);
  char*      after     = base + repB + rsB + auxB + pairB;
  int*       pos       = (int*)after;
  float*     xtmp      = (float*)after;  // aliased; lifetimes disjoint

  hipMemsetAsync(rep, 0, repB, stream);

  int E4 = E >> 2;
  int hb  = (E4 + 1023) / 1024;
  int fbk = (E4 + 511) / 512;
  int nb  = (N + 1023) / 1024;
  int nfb = (N + 3) / 4;

  hist_kernel<<<hb, 256, 0, stream>>>((const vi4*)snd, rep, (vi4*)pos,
                                      snd, pos, N, E);
  scanA_kernel<<<nb, 1024, 0, stream>>>(rep, row_start, btot, N);
  scanB_kernel<<<1, 64, 0, stream>>>(btot, boff, row_start, nb, N);
  scanC_kernel<<<nb, 1024, 0, stream>>>(row_start, boff, rep, N);
  fill_kernel<<<fbk, 256, 0, stream>>>((const vi4*)snd, (const vi4*)rcv,
                                       (const vf4*)ew, (const vi4*)pos,
                                       rep, pair, snd, rcv, ew, pos, N, E);

  // step 1: nodes -> xtmp ; step 2: xtmp -> out (not in-place: reads neighbors)
  flowp_kernel<<<nfb, 256, 0, stream>>>(nodes, row_start, pair, tsq, dsq, xtmp, N);
  flowp_kernel<<<nfb, 256, 0, stream>>>(xtmp, row_start, pair, tsq, dsq, out, N);
}